// Round 4
// baseline (226.795 us; speedup 1.0000x reference)
//
#include <hip/hip_runtime.h>
#include <hip/hip_bf16.h>

// MHA forward: B=4, S=2048, D=1024, H=16, DH=64. fp32 in/out, bf16 MFMA inside.

#define Bq 4
#define Sq 2048
#define Dq 1024
#define Hq 16
#define DHq 64

typedef __attribute__((ext_vector_type(8))) short short8;
typedef __attribute__((ext_vector_type(4))) float f32x4;
typedef __attribute__((ext_vector_type(4))) unsigned short ushort4v;
typedef __attribute__((ext_vector_type(2))) unsigned int uint2v;

static __device__ __forceinline__ unsigned short f2bfu(float f) {
    union { __hip_bfloat16 h; unsigned short u; } cv;
    cv.h = __float2bfloat16(f);
    return cv.u;
}
static __device__ __forceinline__ unsigned int pkbf(float lo, float hi) {
    return (unsigned int)f2bfu(lo) | ((unsigned int)f2bfu(hi) << 16);
}

// ---------------------------------------------------------------------------
// Fragment-order layouts (per bh block of 131072 ushorts):
//  Q/K (A-frag over [s,d]): off = (s>>4)*1024 + (d>>5)*512 + ((d>>3)&3)*128
//                                 + (s&15)*8 + (d&7)
//  V   (A-frag over [d,s]): off = (s>>6)*4096 + ((d>>4)&3)*1024 + ((s>>5)&1)*512
//                                 + ((s>>3)&3)*128 + (d&15)*8 + (s&7)
// so a 64-key tile is 4096 consecutive elems and per-lane fragment reads are
// tile_base + lane*16B (fully coalesced / linear for global_load_lds).
// ---------------------------------------------------------------------------

// ---------------------------------------------------------------------------
// Kernel 1: QKV projections. Y = X @ W^T, scattered to fragment-order layouts.
//  VT=false: Q (z=0, scaled by log2e/8 -> exp2-domain softmax) and K (z=1)
//  VT=true : V via operand-swapped MFMA (acc holds V^T)
// ---------------------------------------------------------------------------
template<bool VT>
__global__ __launch_bounds__(256) void qkv_gemm(
    const float* __restrict__ X,
    const float* __restrict__ W0, const float* __restrict__ W1,
    unsigned short* __restrict__ o0, unsigned short* __restrict__ o1)
{
    __shared__ unsigned short As[128][72];
    __shared__ unsigned short Bs[128][72];

    const float* W = blockIdx.z ? W1 : W0;
    unsigned short* out = blockIdx.z ? o1 : o0;
    // Q: fold 1/sqrt(DH) * log2(e) so attention softmax works in exp2 domain
    const float oscale = (!VT && blockIdx.z == 0) ? 0.180336880f : 1.0f;

    const int m0 = blockIdx.x * 128;
    const int n0 = blockIdx.y * 128;
    const int t = threadIdx.x;
    const int lane = t & 63;
    const int wave = t >> 6;
    const int wm = wave >> 1, wn = wave & 1;
    const int g = lane >> 4, c = lane & 15;

    f32x4 acc[4][4] = {};

    const int lrow = t >> 4;    // 0..15
    const int lcol4 = t & 15;   // float4 column

    for (int kt = 0; kt < 16; ++kt) {
        const int kbase = kt * 64;
#pragma unroll
        for (int p = 0; p < 8; ++p) {
            const int row = lrow + p * 16;
            const float4 a4 = *reinterpret_cast<const float4*>(
                &X[(size_t)(m0 + row) * 1024 + kbase + lcol4 * 4]);
            const float4 b4 = *reinterpret_cast<const float4*>(
                &W[(size_t)(n0 + row) * 1024 + kbase + lcol4 * 4]);
            ushort4v av, bv;
            av[0] = f2bfu(a4.x); av[1] = f2bfu(a4.y); av[2] = f2bfu(a4.z); av[3] = f2bfu(a4.w);
            bv[0] = f2bfu(b4.x); bv[1] = f2bfu(b4.y); bv[2] = f2bfu(b4.z); bv[3] = f2bfu(b4.w);
            *reinterpret_cast<ushort4v*>(&As[row][lcol4 * 4]) = av;
            *reinterpret_cast<ushort4v*>(&Bs[row][lcol4 * 4]) = bv;
        }
        __syncthreads();
#pragma unroll
        for (int ks = 0; ks < 2; ++ks) {
            short8 bf[4];
#pragma unroll
            for (int nt = 0; nt < 4; ++nt)
                bf[nt] = *reinterpret_cast<const short8*>(&Bs[wn * 64 + nt * 16 + c][ks * 32 + g * 8]);
#pragma unroll
            for (int mt = 0; mt < 4; ++mt) {
                const short8 af = *reinterpret_cast<const short8*>(&As[wm * 64 + mt * 16 + c][ks * 32 + g * 8]);
#pragma unroll
                for (int nt = 0; nt < 4; ++nt) {
                    if (VT)
                        acc[mt][nt] = __builtin_amdgcn_mfma_f32_16x16x32_bf16(bf[nt], af, acc[mt][nt], 0, 0, 0);
                    else
                        acc[mt][nt] = __builtin_amdgcn_mfma_f32_16x16x32_bf16(af, bf[nt], acc[mt][nt], 0, 0, 0);
                }
            }
        }
        __syncthreads();
    }

#pragma unroll
    for (int mt = 0; mt < 4; ++mt)
#pragma unroll
        for (int nt = 0; nt < 4; ++nt)
#pragma unroll
            for (int r = 0; r < 4; ++r) {
                if (VT) {
                    const int m = m0 + wm * 64 + mt * 16 + c;           // token
                    const int n = n0 + wn * 64 + nt * 16 + g * 4 + r;   // feature
                    const int bb = m >> 11, s = m & 2047;
                    const int h = n >> 6, d = n & 63;
                    const size_t off = (size_t)(bb * Hq + h) * 131072
                        + (s >> 6) * 4096 + ((d >> 4) & 3) * 1024 + ((s >> 5) & 1) * 512
                        + ((s >> 3) & 3) * 128 + (d & 15) * 8 + (s & 7);
                    out[off] = f2bfu(acc[mt][nt][r]);
                } else {
                    const int m = m0 + wm * 64 + mt * 16 + g * 4 + r;   // token
                    const int n = n0 + wn * 64 + nt * 16 + c;           // feature
                    const int bb = m >> 11, s = m & 2047;
                    const int h = n >> 6, d = n & 63;
                    const size_t off = (size_t)(bb * Hq + h) * 131072
                        + (s >> 4) * 1024 + (d >> 5) * 512 + ((d >> 3) & 3) * 128
                        + (s & 15) * 8 + (d & 7);
                    out[off] = f2bfu(acc[mt][nt][r] * oscale);
                }
            }
}

// ---------------------------------------------------------------------------
// Kernel 2: causal flash attention.
// 512 blocks (64 bh x 8 q-block pairs); block = 128 q-rows; wave = 32 q-rows
// (2 q-tiles of 16). K/V 64-key tiles double-buffered in LDS via
// global_load_lds, shared by all 4 waves (one barrier per tile).
// Softmax lane-local in exp2 domain (scale pre-folded into Q).
// ---------------------------------------------------------------------------
static __device__ __forceinline__ void stage_kv(
    const unsigned short* __restrict__ Kb, const unsigned short* __restrict__ Vb,
    int kb, unsigned short* kl, unsigned short* vl, int wave, int lane)
{
    const int goff = wave * 1024 + lane * 8;   // elems
    const unsigned short* gk = Kb + (size_t)kb * 4096 + goff;
    const unsigned short* gv = Vb + (size_t)kb * 4096 + goff;
    unsigned short* lk = kl + wave * 1024;     // wave-uniform LDS base
    unsigned short* lv = vl + wave * 1024;
#pragma unroll
    for (int j = 0; j < 2; ++j) {
        __builtin_amdgcn_global_load_lds(
            (const __attribute__((address_space(1))) unsigned int*)(gk + j * 512),
            (__attribute__((address_space(3))) unsigned int*)(lk + j * 512), 16, 0, 0);
        __builtin_amdgcn_global_load_lds(
            (const __attribute__((address_space(1))) unsigned int*)(gv + j * 512),
            (__attribute__((address_space(3))) unsigned int*)(lv + j * 512), 16, 0, 0);
    }
}

static __device__ __forceinline__ void qt_step(
    const short8* kf, const short8* vf,
    const short8 q0, const short8 q1,
    int rel, int g, int c,
    unsigned short (*PtW)[72],
    float& m_r, float& l_r, f32x4* oacc)
{
    // S^T = K · Q^T  (acc: row=key_local, col=q=c), values in log2 domain
    f32x4 st[4] = {};
#pragma unroll
    for (int k2 = 0; k2 < 4; ++k2) {
        st[k2] = __builtin_amdgcn_mfma_f32_16x16x32_bf16(kf[2 * k2],     q0, st[k2], 0, 0, 0);
        st[k2] = __builtin_amdgcn_mfma_f32_16x16x32_bf16(kf[2 * k2 + 1], q1, st[k2], 0, 0, 0);
    }

    float p[4][4];
    if (rel < 4) {                       // diagonal tile: causal mask
        const int lim = rel * 16 + c;
#pragma unroll
        for (int kt = 0; kt < 4; ++kt)
#pragma unroll
            for (int r = 0; r < 4; ++r)
                p[kt][r] = (kt * 16 + g * 4 + r > lim) ? -3.0e38f : st[kt][r];
    } else {
#pragma unroll
        for (int kt = 0; kt < 4; ++kt)
#pragma unroll
            for (int r = 0; r < 4; ++r) p[kt][r] = st[kt][r];
    }

    float mx = p[0][0];
#pragma unroll
    for (int kt = 0; kt < 4; ++kt)
#pragma unroll
        for (int r = 0; r < 4; ++r) mx = fmaxf(mx, p[kt][r]);
    mx = fmaxf(mx, __shfl_xor(mx, 16));
    mx = fmaxf(mx, __shfl_xor(mx, 32));
    if (__any(mx > m_r + 8.f)) {         // defer-max (P bounded by 2^8)
        const float mn = fmaxf(m_r, mx);
        const float alpha = exp2f(m_r - mn);
        l_r *= alpha;
#pragma unroll
        for (int dt = 0; dt < 4; ++dt)
#pragma unroll
            for (int r = 0; r < 4; ++r) oacc[dt][r] *= alpha;
        m_r = mn;
    }
    float rs = 0.f;
#pragma unroll
    for (int kt = 0; kt < 4; ++kt)
#pragma unroll
        for (int r = 0; r < 4; ++r) {
            const float e = exp2f(p[kt][r] - m_r);
            p[kt][r] = e;
            rs += e;
        }
    rs += __shfl_xor(rs, 16);
    rs += __shfl_xor(rs, 32);
    l_r += rs;

    // P^T -> bf16 -> per-wave LDS repack (same-wave, no barrier)
#pragma unroll
    for (int kt = 0; kt < 4; ++kt) {
        uint2v u;
        u[0] = pkbf(p[kt][0], p[kt][1]);
        u[1] = pkbf(p[kt][2], p[kt][3]);
        *reinterpret_cast<uint2v*>(&PtW[c][kt * 16 + g * 4]) = u;
    }
    const short8 pb0 = *reinterpret_cast<const short8*>(&PtW[c][g * 8]);
    const short8 pb1 = *reinterpret_cast<const short8*>(&PtW[c][32 + g * 8]);

    // O^T += V^T · P^T
#pragma unroll
    for (int dt = 0; dt < 4; ++dt) {
        oacc[dt] = __builtin_amdgcn_mfma_f32_16x16x32_bf16(vf[2 * dt],     pb0, oacc[dt], 0, 0, 0);
        oacc[dt] = __builtin_amdgcn_mfma_f32_16x16x32_bf16(vf[2 * dt + 1], pb1, oacc[dt], 0, 0, 0);
    }
}

__global__ __launch_bounds__(256, 2) void attn(
    const unsigned short* __restrict__ Qf, const unsigned short* __restrict__ Kf,
    const unsigned short* __restrict__ Vf, unsigned short* __restrict__ O)
{
    __shared__ unsigned short Kl[2][4096];
    __shared__ unsigned short Vl[2][4096];
    __shared__ unsigned short Pt[4][2][16][72];

    // bid = xcd(3b) | pair(3b)<<3 | bh_hi(3b)<<6 : one bh's K/V pinned to one
    // XCD's L2; every block does exactly 34 kv-tile iterations.
    const int bid = blockIdx.x;
    const int pair = (bid >> 3) & 7;
    const int bh = (bid & 7) | ((bid >> 6) << 3);

    const int t = threadIdx.x, lane = t & 63, wave = t >> 6;
    const int g = lane >> 4, c = lane & 15;
    const size_t base = (size_t)bh * (Sq * DHq);
    const unsigned short* Qb = Qf + base;
    const unsigned short* Kb = Kf + base;
    const unsigned short* Vb = Vf + base;
    const int b = bh >> 4, h = bh & 15;

#pragma unroll 1
    for (int pp = 0; pp < 2; ++pp) {
        const int qi = pp ? (15 - pair) : pair;     // 128-row q-block
        const int qtA = qi * 8 + wave * 2;          // wave's two 16-row q-tiles
        const int qtB = qtA + 1;

        const unsigned short* qpA = Qb + (size_t)qtA * 1024 + lane * 8;
        const unsigned short* qpB = Qb + (size_t)qtB * 1024 + lane * 8;
        const short8 qA0 = *reinterpret_cast<const short8*>(qpA);
        const short8 qA1 = *reinterpret_cast<const short8*>(qpA + 512);
        const short8 qB0 = *reinterpret_cast<const short8*>(qpB);
        const short8 qB1 = *reinterpret_cast<const short8*>(qpB + 512);

        float mA = -3.0e38f, lA = 0.f, mB = -3.0e38f, lB = 0.f;
        f32x4 oA[4] = {}, oB[4] = {};

        const int ibmax  = 2 * qi + 1;              // block's last kv tile
        const int ibmaxw = 2 * qi + (wave >> 1);    // this wave's last kv tile

        stage_kv(Kb, Vb, 0, Kl[0], Vl[0], wave, lane);
        __syncthreads();

#pragma unroll 1
        for (int ib = 0; ib <= ibmax; ++ib) {
            const int cur = ib & 1;
            if (ib < ibmax)
                stage_kv(Kb, Vb, ib + 1, Kl[cur ^ 1], Vl[cur ^ 1], wave, lane);

            if (ib <= ibmaxw) {
                short8 kf[8], vf[8];
#pragma unroll
                for (int i = 0; i < 8; ++i)
                    kf[i] = *reinterpret_cast<const short8*>(&Kl[cur][lane * 8 + i * 512]);
#pragma unroll
                for (int i = 0; i < 8; ++i)
                    vf[i] = *reinterpret_cast<const short8*>(&Vl[cur][lane * 8 + i * 512]);

                qt_step(kf, vf, qA0, qA1, qtA - ib * 4, g, c, Pt[wave][0], mA, lA, oA);
                qt_step(kf, vf, qB0, qB1, qtB - ib * 4, g, c, Pt[wave][1], mB, lB, oB);
            }
            __syncthreads();
        }

        // epilogue: O[b, q, h*64+d] = O^T[d][q] / l, packed 8B stores
        const float rlA = 1.0f / lA;
        const float rlB = 1.0f / lB;
        const size_t orowA = ((size_t)b * Sq + qtA * 16 + c) * Dq + h * 64;
        const size_t orowB = ((size_t)b * Sq + qtB * 16 + c) * Dq + h * 64;
#pragma unroll
        for (int dt = 0; dt < 4; ++dt) {
            uint2v uA, uB;
            uA[0] = pkbf(oA[dt][0] * rlA, oA[dt][1] * rlA);
            uA[1] = pkbf(oA[dt][2] * rlA, oA[dt][3] * rlA);
            uB[0] = pkbf(oB[dt][0] * rlB, oB[dt][1] * rlB);
            uB[1] = pkbf(oB[dt][2] * rlB, oB[dt][3] * rlB);
            *reinterpret_cast<uint2v*>(&O[orowA + dt * 16 + g * 4]) = uA;
            *reinterpret_cast<uint2v*>(&O[orowB + dt * 16 + g * 4]) = uB;
        }
    }
}

// ---------------------------------------------------------------------------
// Kernel 3: output projection. out = Z @ Wo^T + bo (fp32 out).
// ---------------------------------------------------------------------------
__global__ __launch_bounds__(256) void proj_gemm(
    const unsigned short* __restrict__ Z, const float* __restrict__ Wo,
    const float* __restrict__ bo, float* __restrict__ out)
{
    __shared__ unsigned short As[128][72];
    __shared__ unsigned short Bs[128][72];

    const int m0 = blockIdx.x * 128;
    const int n0 = blockIdx.y * 128;
    const int t = threadIdx.x;
    const int lane = t & 63;
    const int wave = t >> 6;
    const int wm = wave >> 1, wn = wave & 1;
    const int g = lane >> 4, c = lane & 15;

    f32x4 acc[4][4] = {};

    const int lrow = t >> 4, lcol4 = t & 15;      // B staging (fp32 source)
    const int arow = t >> 3, acol8 = t & 7;       // A staging (bf16 source)

    for (int kt = 0; kt < 16; ++kt) {
        const int kbase = kt * 64;
#pragma unroll
        for (int p = 0; p < 4; ++p) {
            const int row = arow + p * 32;
            const short8 a8 = *reinterpret_cast<const short8*>(
                &Z[(size_t)(m0 + row) * 1024 + kbase + acol8 * 8]);
            *reinterpret_cast<short8*>(&As[row][acol8 * 8]) = a8;
        }
#pragma unroll
        for (int p = 0; p < 8; ++p) {
            const int row = lrow + p * 16;
            const float4 b4 = *reinterpret_cast<const float4*>(
                &Wo[(size_t)(n0 + row) * 1024 + kbase + lcol4 * 4]);
            ushort4v bv;
            bv[0] = f2bfu(b4.x); bv[1] = f2bfu(b4.y); bv[2] = f2bfu(b4.z); bv[3] = f2bfu(b4.w);
            *reinterpret_cast<ushort4v*>(&Bs[row][lcol4 * 4]) = bv;
        }
        __syncthreads();
#pragma unroll
        for (int ks = 0; ks < 2; ++ks) {
            short8 bf[4];
#pragma unroll
            for (int nt = 0; nt < 4; ++nt)
                bf[nt] = *reinterpret_cast<const short8*>(&Bs[wn * 64 + nt * 16 + c][ks * 32 + g * 8]);
#pragma unroll
            for (int mt = 0; mt < 4; ++mt) {
                const short8 af = *reinterpret_cast<const short8*>(&As[wm * 64 + mt * 16 + c][ks * 32 + g * 8]);
#pragma unroll
                for (int nt = 0; nt < 4; ++nt)
                    acc[mt][nt] = __builtin_amdgcn_mfma_f32_16x16x32_bf16(af, bf[nt], acc[mt][nt], 0, 0, 0);
            }
        }
        __syncthreads();
    }

#pragma unroll
    for (int nt = 0; nt < 4; ++nt) {
        const int n = n0 + wn * 64 + nt * 16 + c;
        const float bias = bo[n];
#pragma unroll
        for (int mt = 0; mt < 4; ++mt)
#pragma unroll
            for (int r = 0; r < 4; ++r) {
                const int m = m0 + wm * 64 + mt * 16 + g * 4 + r;
                out[(size_t)m * 1024 + n] = acc[mt][nt][r] + bias;
            }
    }
}

// ---------------------------------------------------------------------------
extern "C" void kernel_launch(void* const* d_in, const int* in_sizes, int n_in,
                              void* d_out, int out_size, void* d_ws, size_t ws_size,
                              hipStream_t stream) {
    const float* X  = (const float*)d_in[0];
    const float* Wq = (const float*)d_in[1];
    const float* Wk = (const float*)d_in[2];
    const float* Wv = (const float*)d_in[3];
    const float* Wo = (const float*)d_in[4];
    const float* bo = (const float*)d_in[5];
    float* out = (float*)d_out;

    const size_t elems = (size_t)Bq * Hq * Sq * DHq;  // 8,388,608
    unsigned short* q  = (unsigned short*)d_ws;
    unsigned short* k  = q + elems;
    unsigned short* vt = k + elems;
    unsigned short* o  = vt + elems;

    dim3 gq((Bq * Sq) / 128, Dq / 128, 2);
    qkv_gemm<false><<<gq, 256, 0, stream>>>(X, Wq, Wk, q, k);
    dim3 gv((Bq * Sq) / 128, Dq / 128, 1);
    qkv_gemm<true><<<gv, 256, 0, stream>>>(X, Wv, Wv, vt, vt);

    attn<<<dim3(512), 256, 0, stream>>>(q, k, vt, o);

    dim3 gp((Bq * Sq) / 128, Dq / 128, 1);
    proj_gemm<<<gp, 256, 0, stream>>>(o, Wo, bo, out);
}

// Round 5
// 212.524 us; speedup vs baseline: 1.0672x; 1.0672x over previous
//
#include <hip/hip_runtime.h>
#include <hip/hip_bf16.h>

// MHA forward: B=4, S=2048, D=1024, H=16, DH=64. fp32 in/out, bf16 MFMA inside.

#define Bq 4
#define Sq 2048
#define Dq 1024
#define Hq 16
#define DHq 64

typedef __attribute__((ext_vector_type(8))) short short8;
typedef __attribute__((ext_vector_type(4))) float f32x4;
typedef __attribute__((ext_vector_type(4))) unsigned short ushort4v;
typedef __attribute__((ext_vector_type(2))) unsigned int uint2v;

static __device__ __forceinline__ unsigned short f2bfu(float f) {
    union { __hip_bfloat16 h; unsigned short u; } cv;
    cv.h = __float2bfloat16(f);
    return cv.u;
}
static __device__ __forceinline__ unsigned int cvtpk(float lo, float hi) {
    unsigned int r;
    asm("v_cvt_pk_bf16_f32 %0, %1, %2" : "=v"(r) : "v"(lo), "v"(hi));
    return r;
}

// ---------------------------------------------------------------------------
// Kernel 0: fp32 -> bf16 prepass for X and the four weight matrices.
// ---------------------------------------------------------------------------
__global__ __launch_bounds__(256) void tobf16(
    const float* __restrict__ X, const float* __restrict__ W0,
    const float* __restrict__ W1, const float* __restrict__ W2,
    const float* __restrict__ W3,
    unsigned short* __restrict__ xb, unsigned short* __restrict__ wb)
{
    const size_t i = ((size_t)blockIdx.x * 256 + threadIdx.x) * 8;
    const size_t NX = (size_t)8388608;
    const float* src; unsigned short* dst; size_t off;
    if (i < NX) { src = X; dst = xb; off = i; }
    else {
        const size_t j = i - NX;
        const int w = (int)(j >> 20);
        off = j & 1048575;
        src = (w == 0) ? W0 : (w == 1) ? W1 : (w == 2) ? W2 : W3;
        dst = wb + ((size_t)w << 20);
    }
    const float4 a = *reinterpret_cast<const float4*>(src + off);
    const float4 b = *reinterpret_cast<const float4*>(src + off + 4);
    short8 v;
    v[0] = (short)f2bfu(a.x); v[1] = (short)f2bfu(a.y);
    v[2] = (short)f2bfu(a.z); v[3] = (short)f2bfu(a.w);
    v[4] = (short)f2bfu(b.x); v[5] = (short)f2bfu(b.y);
    v[6] = (short)f2bfu(b.z); v[7] = (short)f2bfu(b.w);
    *reinterpret_cast<short8*>(dst + off) = v;
}

// ---------------------------------------------------------------------------
// Fragment-order layouts (per bh block of 131072 ushorts):
//  Q/K (A-frag over [s,d]): off = (s>>4)*1024 + (d>>5)*512 + ((d>>3)&3)*128
//                                 + (s&15)*8 + (d&7)
//  V   (A-frag over [d,s]): off = (s>>6)*4096 + ((d>>4)&3)*1024 + ((s>>5)&1)*512
//                                 + ((s>>3)&3)*128 + (d&15)*8 + (s&7)
// ---------------------------------------------------------------------------

// ---------------------------------------------------------------------------
// Kernel 1: projection GEMM, m97-style (global_load_lds staging, bf16 inputs).
// C = A · W^T, 128x128 tile, BK=64, 4 waves (2x2), 4x4 MFMAs each.
//  MODE 0: z=0 -> Q (scaled log2e/8, exp2-domain softmax), z=1 -> K; frag-order out
//  MODE 1: V^T via operand-swapped MFMA; frag-order out
//  MODE 2: out = A·Wo^T + bo, fp32
// ---------------------------------------------------------------------------
template<int MODE>
__global__ __launch_bounds__(256) void mm(
    const unsigned short* __restrict__ Ab, const unsigned short* __restrict__ Wall,
    unsigned short* __restrict__ oq, unsigned short* __restrict__ ok,
    unsigned short* __restrict__ ovt, const float* __restrict__ bo,
    float* __restrict__ outf)
{
    __shared__ unsigned short As[128 * 64];
    __shared__ unsigned short Bs[128 * 64];

    const int z = (MODE == 0) ? blockIdx.z : 0;
    const int widx = (MODE == 0) ? z : (MODE == 1) ? 2 : 3;
    const unsigned short* W = Wall + ((size_t)widx << 20);

    const int m0 = blockIdx.x * 128, n0 = blockIdx.y * 128;
    const int t = threadIdx.x, lane = t & 63, wave = t >> 6;
    const int g = lane >> 4, c = lane & 15;
    const int wm = wave >> 1, wn = wave & 1;
    const int r8 = lane >> 3, c8 = lane & 7;

    f32x4 acc[4][4] = {};

    for (int kt = 0; kt < 16; ++kt) {
        const int kb = kt * 64;
#pragma unroll
        for (int p = 0; p < 4; ++p) {
            const int rowb = wave * 8 + p * 32;
            const unsigned short* ga = Ab + (size_t)(m0 + rowb + r8) * 1024 + kb + c8 * 8;
            const unsigned short* gb = W  + (size_t)(n0 + rowb + r8) * 1024 + kb + c8 * 8;
            __builtin_amdgcn_global_load_lds(
                (const __attribute__((address_space(1))) unsigned int*)ga,
                (__attribute__((address_space(3))) unsigned int*)(As + rowb * 64), 16, 0, 0);
            __builtin_amdgcn_global_load_lds(
                (const __attribute__((address_space(1))) unsigned int*)gb,
                (__attribute__((address_space(3))) unsigned int*)(Bs + rowb * 64), 16, 0, 0);
        }
        __syncthreads();
#pragma unroll
        for (int ks = 0; ks < 2; ++ks) {
            short8 bf[4];
#pragma unroll
            for (int nt = 0; nt < 4; ++nt)
                bf[nt] = *reinterpret_cast<const short8*>(&Bs[(wn * 64 + nt * 16 + c) * 64 + ks * 32 + g * 8]);
#pragma unroll
            for (int mt = 0; mt < 4; ++mt) {
                const short8 af = *reinterpret_cast<const short8*>(&As[(wm * 64 + mt * 16 + c) * 64 + ks * 32 + g * 8]);
#pragma unroll
                for (int nt = 0; nt < 4; ++nt) {
                    if (MODE == 1)
                        acc[mt][nt] = __builtin_amdgcn_mfma_f32_16x16x32_bf16(bf[nt], af, acc[mt][nt], 0, 0, 0);
                    else
                        acc[mt][nt] = __builtin_amdgcn_mfma_f32_16x16x32_bf16(af, bf[nt], acc[mt][nt], 0, 0, 0);
                }
            }
        }
        __syncthreads();
    }

    if (MODE == 2) {
#pragma unroll
        for (int nt = 0; nt < 4; ++nt) {
            const int n = n0 + wn * 64 + nt * 16 + c;
            const float bias = bo[n];
#pragma unroll
            for (int mt = 0; mt < 4; ++mt)
#pragma unroll
                for (int r = 0; r < 4; ++r) {
                    const int m = m0 + wm * 64 + mt * 16 + g * 4 + r;
                    outf[(size_t)m * 1024 + n] = acc[mt][nt][r] + bias;
                }
        }
    } else if (MODE == 1) {
#pragma unroll
        for (int mt = 0; mt < 4; ++mt)
#pragma unroll
            for (int nt = 0; nt < 4; ++nt)
#pragma unroll
                for (int r = 0; r < 4; ++r) {
                    const int m = m0 + wm * 64 + mt * 16 + c;           // token
                    const int n = n0 + wn * 64 + nt * 16 + g * 4 + r;   // feature
                    const int bb = m >> 11, s = m & 2047;
                    const int h = n >> 6, d = n & 63;
                    const size_t off = (size_t)(bb * Hq + h) * 131072
                        + (s >> 6) * 4096 + ((d >> 4) & 3) * 1024 + ((s >> 5) & 1) * 512
                        + ((s >> 3) & 3) * 128 + (d & 15) * 8 + (s & 7);
                    ovt[off] = f2bfu(acc[mt][nt][r]);
                }
    } else {
        // Q: fold 1/sqrt(DH) * log2(e) so attention softmax works in exp2 domain
        const float oscale = (z == 0) ? 0.180336880f : 1.0f;
        unsigned short* out = z ? ok : oq;
#pragma unroll
        for (int mt = 0; mt < 4; ++mt)
#pragma unroll
            for (int nt = 0; nt < 4; ++nt)
#pragma unroll
                for (int r = 0; r < 4; ++r) {
                    const int m = m0 + wm * 64 + mt * 16 + g * 4 + r;   // token
                    const int n = n0 + wn * 64 + nt * 16 + c;           // feature
                    const int bb = m >> 11, s = m & 2047;
                    const int h = n >> 6, d = n & 63;
                    const size_t off = (size_t)(bb * Hq + h) * 131072
                        + (s >> 4) * 1024 + (d >> 5) * 512 + ((d >> 3) & 3) * 128
                        + (s & 15) * 8 + (d & 7);
                    out[off] = f2bfu(acc[mt][nt][r] * oscale);
                }
    }
}

// ---------------------------------------------------------------------------
// Kernel 2: causal flash attention, barrier-free, fragment-order inputs.
// 1024 blocks; block handles qb=pair then qb=31-pair (exactly 33 iterations).
// K register double-buffered; V issued right after QK; sched_barrier(0) pins
// loads above softmax. Softmax: exp2 domain; common path = local fmax tree +
// ballot check only (cross-lane reduce only on rare rescale); row-sum l via
// ones-fragment MFMA into a 5th accumulator; P-pack via v_cvt_pk_bf16_f32.
// ---------------------------------------------------------------------------
#define ATTN_STEP(KC, KN, IB)                                                  \
  {                                                                            \
    f32x4 st[4] = {};                                                          \
    _Pragma("unroll")                                                          \
    for (int k2 = 0; k2 < 4; ++k2) {                                           \
      st[k2] = __builtin_amdgcn_mfma_f32_16x16x32_bf16(KC[2 * k2],     qf0, st[k2], 0, 0, 0); \
      st[k2] = __builtin_amdgcn_mfma_f32_16x16x32_bf16(KC[2 * k2 + 1], qf1, st[k2], 0, 0, 0); \
    }                                                                          \
    short8 vf[8];                                                              \
    {                                                                          \
      const unsigned short* vp = Vb + (size_t)(IB) * 4096 + lane * 8;          \
      _Pragma("unroll")                                                        \
      for (int i = 0; i < 8; ++i) vf[i] = *reinterpret_cast<const short8*>(vp + i * 512); \
    }                                                                          \
    if ((IB) < qb) {                                                           \
      const unsigned short* kp = Kb + (size_t)((IB) + 1) * 4096 + lane * 8;    \
      _Pragma("unroll")                                                        \
      for (int i = 0; i < 8; ++i) KN[i] = *reinterpret_cast<const short8*>(kp + i * 512); \
    }                                                                          \
    __builtin_amdgcn_sched_barrier(0);                                         \
    float p[4][4];                                                             \
    const bool diag = ((IB) == qb);                                            \
    _Pragma("unroll")                                                          \
    for (int kt = 0; kt < 4; ++kt)                                             \
      _Pragma("unroll")                                                        \
      for (int r = 0; r < 4; ++r) {                                            \
        float sv = st[kt][r];                                                  \
        if (diag && (kt * 16 + g * 4 + r > qloc)) sv = -3.0e38f;               \
        p[kt][r] = sv;                                                         \
      }                                                                        \
    float t0 = fmaxf(fmaxf(p[0][0], p[0][1]), fmaxf(p[0][2], p[0][3]));        \
    float t1 = fmaxf(fmaxf(p[1][0], p[1][1]), fmaxf(p[1][2], p[1][3]));        \
    float t2 = fmaxf(fmaxf(p[2][0], p[2][1]), fmaxf(p[2][2], p[2][3]));        \
    float t3 = fmaxf(fmaxf(p[3][0], p[3][1]), fmaxf(p[3][2], p[3][3]));        \
    const float mloc = fmaxf(fmaxf(t0, t1), fmaxf(t2, t3));                    \
    if (__builtin_expect(__any(mloc > m_r + 8.f), 0)) {                        \
      float mx = fmaxf(mloc, __shfl_xor(mloc, 16));                            \
      mx = fmaxf(mx, __shfl_xor(mx, 32));                                      \
      const float mn = fmaxf(m_r, mx);                                         \
      const float alpha = exp2f(m_r - mn);                                     \
      _Pragma("unroll")                                                        \
      for (int dt = 0; dt < 4; ++dt)                                           \
        _Pragma("unroll")                                                      \
        for (int r = 0; r < 4; ++r) oacc[dt][r] *= alpha;                      \
      _Pragma("unroll")                                                        \
      for (int r = 0; r < 4; ++r) lacc[r] *= alpha;                            \
      m_r = mn;                                                                \
    }                                                                          \
    _Pragma("unroll")                                                          \
    for (int kt = 0; kt < 4; ++kt) {                                           \
      uint2v u;                                                                \
      u[0] = cvtpk(exp2f(p[kt][0] - m_r), exp2f(p[kt][1] - m_r));              \
      u[1] = cvtpk(exp2f(p[kt][2] - m_r), exp2f(p[kt][3] - m_r));              \
      *reinterpret_cast<uint2v*>(&Pt[wave][c][kt * 16 + g * 4]) = u;           \
    }                                                                          \
    const short8 pb0 = *reinterpret_cast<const short8*>(&Pt[wave][c][g * 8]);  \
    const short8 pb1 = *reinterpret_cast<const short8*>(&Pt[wave][c][32 + g * 8]); \
    _Pragma("unroll")                                                          \
    for (int dt = 0; dt < 4; ++dt) {                                           \
      oacc[dt] = __builtin_amdgcn_mfma_f32_16x16x32_bf16(vf[2 * dt],     pb0, oacc[dt], 0, 0, 0); \
      oacc[dt] = __builtin_amdgcn_mfma_f32_16x16x32_bf16(vf[2 * dt + 1], pb1, oacc[dt], 0, 0, 0); \
    }                                                                          \
    lacc = __builtin_amdgcn_mfma_f32_16x16x32_bf16(onesf, pb0, lacc, 0, 0, 0); \
    lacc = __builtin_amdgcn_mfma_f32_16x16x32_bf16(onesf, pb1, lacc, 0, 0, 0); \
  }

__global__ __launch_bounds__(256) void attn(
    const unsigned short* __restrict__ Qf, const unsigned short* __restrict__ Kf,
    const unsigned short* __restrict__ Vf, unsigned short* __restrict__ O)
{
    __shared__ unsigned short Pt[4][16][72];

    // bid = xcd(3b) | pair(4b)<<3 | bh_hi(3b)<<7 : all q-work of one bh on one
    // XCD; every block does exactly 33 iterations (qb=pair, then 31-pair).
    const int bid = blockIdx.x;
    const int pair = (bid >> 3) & 15;
    const int bh = (bid & 7) | ((bid >> 7) << 3);

    const int t = threadIdx.x, lane = t & 63, wave = t >> 6;
    const int g = lane >> 4, c = lane & 15;
    const int qloc = wave * 16 + c;
    const size_t base = (size_t)bh * (Sq * DHq);
    const unsigned short* Qb = Qf + base;
    const unsigned short* Kb = Kf + base;
    const unsigned short* Vb = Vf + base;
    const int b = bh >> 4, h = bh & 15;

    short8 onesf;
#pragma unroll
    for (int j = 0; j < 8; ++j) onesf[j] = (short)0x3F80;   // bf16 1.0

#pragma unroll 1
    for (int pp = 0; pp < 2; ++pp) {
        const int qb = pp ? (31 - pair) : pair;
        const int qt = qb * 4 + wave;

        const unsigned short* qp = Qb + (size_t)qt * 1024 + lane * 8;
        const short8 qf0 = *reinterpret_cast<const short8*>(qp);
        const short8 qf1 = *reinterpret_cast<const short8*>(qp + 512);

        float m_r = -3.0e38f;
        f32x4 oacc[4] = {};
        f32x4 lacc = {};

        short8 ka[8], kb2[8];
        {
            const unsigned short* kp = Kb + lane * 8;
#pragma unroll
            for (int i = 0; i < 8; ++i) ka[i] = *reinterpret_cast<const short8*>(kp + i * 512);
        }
        int ib = 0;
        for (;;) {
            ATTN_STEP(ka, kb2, ib); if (ib == qb) break; ++ib;
            ATTN_STEP(kb2, ka, ib); if (ib == qb) break; ++ib;
        }

        const float rl = 1.0f / lacc[0];
        const size_t orow = ((size_t)b * Sq + qt * 16 + c) * Dq + h * 64;
#pragma unroll
        for (int dt = 0; dt < 4; ++dt) {
            uint2v u;
            u[0] = cvtpk(oacc[dt][0] * rl, oacc[dt][1] * rl);
            u[1] = cvtpk(oacc[dt][2] * rl, oacc[dt][3] * rl);
            *reinterpret_cast<uint2v*>(&O[orow + dt * 16 + g * 4]) = u;
        }
    }
}

// ---------------------------------------------------------------------------
extern "C" void kernel_launch(void* const* d_in, const int* in_sizes, int n_in,
                              void* d_out, int out_size, void* d_ws, size_t ws_size,
                              hipStream_t stream) {
    const float* X  = (const float*)d_in[0];
    const float* Wq = (const float*)d_in[1];
    const float* Wk = (const float*)d_in[2];
    const float* Wv = (const float*)d_in[3];
    const float* Wo = (const float*)d_in[4];
    const float* bo = (const float*)d_in[5];
    float* out = (float*)d_out;

    const size_t elems = (size_t)Bq * Hq * Sq * DHq;  // 8,388,608
    unsigned short* q  = (unsigned short*)d_ws;
    unsigned short* k  = q + elems;
    unsigned short* vt = k + elems;
    unsigned short* xo = vt + elems;        // Xb during GEMMs, attn-output after
    unsigned short* wb = xo + elems;        // 4 bf16 weight matrices
    // total ws: 5*16MB + 8MB = 72MB

    tobf16<<<dim3(6144), 256, 0, stream>>>(X, Wq, Wk, Wv, Wo, xo, wb);

    mm<0><<<dim3(64, 8, 2), 256, 0, stream>>>(xo, wb, q, k, nullptr, nullptr, nullptr);
    mm<1><<<dim3(64, 8, 1), 256, 0, stream>>>(xo, wb, nullptr, nullptr, vt, nullptr, nullptr);

    attn<<<dim3(1024), 256, 0, stream>>>(q, k, vt, xo);

    mm<2><<<dim3(64, 8, 1), 256, 0, stream>>>(xo, wb, nullptr, nullptr, nullptr, bo, out);
}